// Round 1
// baseline (218.533 us; speedup 1.0000x reference)
//
#include <hip/hip_runtime.h>
#include <math.h>

// ---------------------------------------------------------------------------
// FrameDockingScoreModel — round 9.
//
// Round-8 state: 77-row x 9 matvec with wave-uniform ws loads scalarized to
// s_load (SGPR=112, VGPR=36), fd8 dispatch ~52 us, VALUBusy 37%, HBM 23%,
// occupancy 50% -> latency-bound: per-wave VALU work (~3000 cyc) / wave slot
// (~8180 cyc) == measured VALUBusy. Waves stall ~60% on vmcnt (input loads,
// L3/HBM latency) and lgkmcnt (s_load batches per GROUP4).
//
// Round-9 change: TWO items per thread (adjacent pair), interleaved in every
// GROUP4. One s_load stream now feeds 72 FMAs instead of 36 (halves SMEM
// requests/item, every lgkm wait hides under the sibling item's FMAs);
// 12 dwordx4 input loads in flight per wave (2x MLP); stores become 12
// dwordx2 (pair outputs contiguous per stream). FMA order per item is
// unchanged -> bitwise-identical numerics. VGPR ~36 -> ~100 (occupancy
// 8 -> ~4 waves/SIMD): trading TLP for ILP since waves were mostly stalled.
// ---------------------------------------------------------------------------

#define K_A   (0.10846522890932808f * 0.24253562503633297f)  // C2_000*C1_000
#define K_B   (0.10846522890932808f * 0.14002800840979312f)  // C2_000*C1_110
#define K_P   (0.06262242910851495f * 0.33333333333333333f)  // C2_110*C1_011
#define K_Q   (0.06262242910851495f * 0.33333333333333333f)  // C2_110*C1_101
#define K_R   (0.06262242910851495f * 0.23570226039551584f)  // C2_110*C1_111
#define K_WB  (0.14907119849998599f * 0.24253562503633297f)  // C2_011*C1_000
#define K_CB  (0.14907119849998599f * 0.14002800840979312f)  // C2_011*C1_110
#define K_WA  (0.14907119849998599f * 0.33333333333333333f)  // C2_101*C1_011
#define K_WBT (0.14907119849998599f * 0.33333333333333333f)  // C2_101*C1_101
#define K_WC  (0.14907119849998599f * 0.23570226039551584f)  // C2_101*C1_111
#define K_WA3 (0.10540925533894598f * 0.33333333333333333f)  // C2_111*C1_011
#define K_WB3 (0.10540925533894598f * 0.33333333333333333f)  // C2_111*C1_101
#define K_WC3 (0.10540925533894598f * 0.23570226039551584f)  // C2_111*C1_111

// ws layout: 80 rows x 9 floats (rows 77..79 zero) = 720, then extras
#define EX_WB   720   // 16
#define EX_CB   736   // 1 (737..739 pad)
#define EX_WA   740   // 16
#define EX_WBT  756   // 16
#define EX_WC   772   // 4
#define EX_WA3  776   // 4
#define EX_WB3  780   // 4
#define EX_WC3  784   // 1
#define N_WS    785

__global__ void fd9_prep(const float* __restrict__ w1_000, const float* __restrict__ w1_110,
                         const float* __restrict__ w1_011, const float* __restrict__ w1_101,
                         const float* __restrict__ w1_111, const float* __restrict__ w2_000,
                         const float* __restrict__ w2_110, const float* __restrict__ w2_011,
                         const float* __restrict__ w2_101, const float* __restrict__ w2_111,
                         float* __restrict__ ws)
{
    int j = blockIdx.x * 256 + threadIdx.x;   // r9: 4 blocks x 256 -> 4 CUs
    if (j >= N_WS) return;
    float val = 0.f;
    if (j < 720) {
        int r = j / 9, c = j - r * 9;
        if (r < 64) {                       // s1(x)s2(x)s3 rows
            int pq = r >> 2, v = r & 3;
            float a = 0.f;
            for (int u = 0; u < 20; ++u)
                a = fmaf(w1_000[pq * 20 + u], w2_000[u * 36 + v * 9 + c], a);
            val = K_A * a;
        } else if (r < 68) {                // dot12*s3 rows
            int v = r - 64; float a = 0.f;
            for (int u = 0; u < 20; ++u)
                a = fmaf(w1_110[u], w2_000[u * 36 + v * 9 + c], a);
            val = K_B * a;
        } else if (r < 72) {                // d23*s1 rows
            int u = r - 68; float a = 0.f;
            for (int m = 0; m < 5; ++m)
                a = fmaf(w1_011[u * 5 + m], w2_110[m * 9 + c], a);
            val = K_P * a;
        } else if (r < 76) {                // d13*s2 rows
            int u = r - 72; float a = 0.f;
            for (int m = 0; m < 5; ++m)
                a = fmaf(w1_101[u * 5 + m], w2_110[m * 9 + c], a);
            val = K_Q * a;
        } else if (r == 76) {               // dtp row
            float a = 0.f;
            for (int m = 0; m < 5; ++m)
                a = fmaf(w1_111[m], w2_110[m * 9 + c], a);
            val = K_R * a;
        }                                   // rows 77..79: zero
    } else {
        int k = j - 720;
        if (k < 16) {                       // WB[pq]
            float a = 0.f;
            for (int u = 0; u < 20; ++u)
                a = fmaf(w2_011[u], w1_000[k * 20 + u], a);
            val = K_WB * a;
        } else if (k == 16) {               // CB
            float a = 0.f;
            for (int u = 0; u < 20; ++u)
                a = fmaf(w2_011[u], w1_110[u], a);
            val = K_CB * a;
        } else if (k >= 20 && k < 36) {     // WA[u*4+v]
            int u = (k - 20) >> 2, v = (k - 20) & 3;
            float a = 0.f;
            for (int m = 0; m < 5; ++m)
                a = fmaf(w1_011[u * 5 + m], w2_101[m * 4 + v], a);
            val = K_WA * a;
        } else if (k >= 36 && k < 52) {     // WBT[u*4+v]
            int u = (k - 36) >> 2, v = (k - 36) & 3;
            float a = 0.f;
            for (int m = 0; m < 5; ++m)
                a = fmaf(w1_101[u * 5 + m], w2_101[m * 4 + v], a);
            val = K_WBT * a;
        } else if (k >= 52 && k < 56) {     // WC[v]
            int v = k - 52; float a = 0.f;
            for (int m = 0; m < 5; ++m)
                a = fmaf(w1_111[m], w2_101[m * 4 + v], a);
            val = K_WC * a;
        } else if (k >= 56 && k < 60) {     // WA3[u]
            int u = k - 56; float a = 0.f;
            for (int m = 0; m < 5; ++m)
                a = fmaf(w2_111[m], w1_011[u * 5 + m], a);
            val = K_WA3 * a;
        } else if (k >= 60 && k < 64) {     // WB3[v]
            int v = k - 60; float a = 0.f;
            for (int m = 0; m < 5; ++m)
                a = fmaf(w2_111[m], w1_101[v * 5 + m], a);
            val = K_WB3 * a;
        } else if (k == 64) {               // WC3
            float a = 0.f;
            for (int m = 0; m < 5; ++m)
                a = fmaf(w2_111[m], w1_111[m], a);
            val = K_WC3 * a;
        }
    }
    ws[j] = val;
}

__global__ __launch_bounds__(256) void
fd9(const float* __restrict__ lig, const float* __restrict__ rec,
    const float* __restrict__ ws, float* __restrict__ out, int n)
{
    const int t = blockIdx.x * 256 + threadIdx.x;
    const size_t iA = (size_t)t * 2;
    if (iA >= (size_t)n) return;
    const bool two = (iA + 1) < (size_t)n;
    const size_t iB = two ? iA + 1 : iA;    // tail: duplicate A (stores guarded)

    // ---- input loads: 12 dwordx4 in flight (2x MLP vs round 8) ----
    float4 lA0, lA1, lA2, rA0, rA1, rA2, lB0, lB1, lB2, rB0, rB1, rB2;
    {
        const float4* LA = (const float4*)(lig + iA * 12);
        const float4* RA = (const float4*)(rec + iA * 12);
        const float4* LB = (const float4*)(lig + iB * 12);
        const float4* RB = (const float4*)(rec + iB * 12);
        lA0 = LA[0]; lA1 = LA[1]; lA2 = LA[2];
        lB0 = LB[0]; lB1 = LB[1]; lB2 = LB[2];
        rA0 = RA[0]; rA1 = RA[1]; rA2 = RA[2];
        rB0 = RB[0]; rB1 = RB[1]; rB2 = RB[2];
    }

    float s1[2][4], s2[2][4], s3[2][4];
    float v1[2][3], v2[2][3], v3[2][3], c12[2][3];
    float dot12[2], d13[2], d23[2], dtp[2];

#pragma unroll
    for (int k = 0; k < 2; ++k) {           // fully unrolled: all indices static
        float4 l0 = k ? lB0 : lA0, l1 = k ? lB1 : lA1, l2 = k ? lB2 : lA2;
        float4 r0 = k ? rB0 : rA0, r1 = k ? rB1 : rA1, r2 = k ? rB2 : rA2;

        float e1x = l0.w - r0.w, e1y = l1.x - r1.x, e1z = l1.y - r1.y;
        float e2x = l1.z - r1.z, e2y = l1.w - r1.w, e2z = l2.x - r2.x;
        float e3x = l2.y - r2.y, e3y = l2.z - r2.z, e3z = l2.w - r2.w;

        float n1 = fmaf(e1x, e1x, fmaf(e1y, e1y, e1z * e1z));
        float n2 = fmaf(e2x, e2x, fmaf(e2y, e2y, e2z * e2z));
        float n3q = fmaf(e3x, e3x, fmaf(e3y, e3y, e3z * e3z));
        float i1 = __builtin_amdgcn_rsqf(n1);
        float i2 = __builtin_amdgcn_rsqf(n2);
        float i3 = __builtin_amdgcn_rsqf(n3q);
        float d1 = n1 * i1, d2 = n2 * i2, d3 = n3q * i3;

        v1[k][0] = e1x * i1; v1[k][1] = e1y * i1; v1[k][2] = e1z * i1;
        v2[k][0] = e2x * i2; v2[k][1] = e2y * i2; v2[k][2] = e2z * i2;
        v3[k][0] = e3x * i3; v3[k][1] = e3y * i3; v3[k][2] = e3z * i3;

        const float coeff = -0.18f;
        const float o1 = 1.6666666f, o2 = 3.3333333f, o3 = 5.f;
        float x;
        x = d1;      s1[k][0] = __expf(coeff * x * x);
        x = d1 - o1; s1[k][1] = __expf(coeff * x * x);
        x = d1 - o2; s1[k][2] = __expf(coeff * x * x);
        x = d1 - o3; s1[k][3] = __expf(coeff * x * x);
        x = d2;      s2[k][0] = __expf(coeff * x * x);
        x = d2 - o1; s2[k][1] = __expf(coeff * x * x);
        x = d2 - o2; s2[k][2] = __expf(coeff * x * x);
        x = d2 - o3; s2[k][3] = __expf(coeff * x * x);
        x = d3;      s3[k][0] = __expf(coeff * x * x);
        x = d3 - o1; s3[k][1] = __expf(coeff * x * x);
        x = d3 - o2; s3[k][2] = __expf(coeff * x * x);
        x = d3 - o3; s3[k][3] = __expf(coeff * x * x);

        dot12[k] = v1[k][0] * v2[k][0] + v1[k][1] * v2[k][1] + v1[k][2] * v2[k][2];
        d13[k]   = v1[k][0] * v3[k][0] + v1[k][1] * v3[k][1] + v1[k][2] * v3[k][2];
        d23[k]   = v2[k][0] * v3[k][0] + v2[k][1] * v3[k][1] + v2[k][2] * v3[k][2];
        c12[k][0] = v1[k][1] * v2[k][2] - v1[k][2] * v2[k][1];
        c12[k][1] = v1[k][2] * v2[k][0] - v1[k][0] * v2[k][2];
        c12[k][2] = v1[k][0] * v2[k][1] - v1[k][1] * v2[k][0];
        dtp[k] = c12[k][0] * v3[k][0] + c12[k][1] * v3[k][1] + c12[k][2] * v3[k][2];
    }

    // ---------------- 77-row matvec, dual items, 18 accumulators ----------
    float acc[2][9] = {{0.f,0.f,0.f,0.f,0.f,0.f,0.f,0.f,0.f},
                       {0.f,0.f,0.f,0.f,0.f,0.f,0.f,0.f,0.f}};

    // One s_load stream (36 dwords) feeds 72 FMAs. FMA order per item is
    // identical to round 8 (r-major, then c) -> same numerics.
#define GROUP4(g, xa0, xa1, xa2, xa3, xb0, xb1, xb2, xb3) do { \
    const float* wp_ = ws + 36 * (g); \
    const float xa_[4] = { (xa0), (xa1), (xa2), (xa3) }; \
    const float xb_[4] = { (xb0), (xb1), (xb2), (xb3) }; \
    _Pragma("unroll") \
    for (int r_ = 0; r_ < 4; ++r_) { \
        _Pragma("unroll") \
        for (int c_ = 0; c_ < 9; ++c_) { \
            const float w_ = wp_[r_ * 9 + c_]; \
            acc[0][c_] = fmaf(xa_[r_], w_, acc[0][c_]); \
            acc[1][c_] = fmaf(xb_[r_], w_, acc[1][c_]); \
        } \
    } \
} while (0)

    const float cb = ws[EX_CB];
    float sg[2] = { dot12[0] * cb, dot12[1] * cb };

#pragma unroll
    for (int p = 0; p < 4; ++p) {
#pragma unroll
        for (int q = 0; q < 4; ++q) {
            const int pq = p * 4 + q;
            const float oA = s1[0][p] * s2[0][q];
            const float oB = s1[1][p] * s2[1][q];
            const float wbq = ws[EX_WB + pq];
            sg[0] = fmaf(oA, wbq, sg[0]);
            sg[1] = fmaf(oB, wbq, sg[1]);
            GROUP4(pq, oA * s3[0][0], oA * s3[0][1], oA * s3[0][2], oA * s3[0][3],
                       oB * s3[1][0], oB * s3[1][1], oB * s3[1][2], oB * s3[1][3]);
        }
    }
    GROUP4(16, dot12[0] * s3[0][0], dot12[0] * s3[0][1], dot12[0] * s3[0][2], dot12[0] * s3[0][3],
               dot12[1] * s3[1][0], dot12[1] * s3[1][1], dot12[1] * s3[1][2], dot12[1] * s3[1][3]);
    GROUP4(17, d23[0] * s1[0][0], d23[0] * s1[0][1], d23[0] * s1[0][2], d23[0] * s1[0][3],
               d23[1] * s1[1][0], d23[1] * s1[1][1], d23[1] * s1[1][2], d23[1] * s1[1][3]);
    GROUP4(18, d13[0] * s2[0][0], d13[0] * s2[0][1], d13[0] * s2[0][2], d13[0] * s2[0][3],
               d13[1] * s2[1][0], d13[1] * s2[1][1], d13[1] * s2[1][2], d13[1] * s2[1][3]);
    {   // row 76 only (77..79 are zero)
        const float* wp = ws + 36 * 19;
#pragma unroll
        for (int c = 0; c < 9; ++c) {
            acc[0][c] = fmaf(dtp[0], wp[c], acc[0][c]);
            acc[1][c] = fmaf(dtp[1], wp[c], acc[1][c]);
        }
    }
#undef GROUP4

    // ---------------- epilogue scalars (dual) ----------------
    float ta[2] = {0.f, 0.f}, tb[2] = {0.f, 0.f};
#pragma unroll
    for (int u = 0; u < 4; ++u) {
        const float a0 = ws[EX_WA + u * 4 + 0], a1 = ws[EX_WA + u * 4 + 1];
        const float a2 = ws[EX_WA + u * 4 + 2], a3 = ws[EX_WA + u * 4 + 3];
        const float b0 = ws[EX_WBT + u * 4 + 0], b1 = ws[EX_WBT + u * 4 + 1];
        const float b2 = ws[EX_WBT + u * 4 + 2], b3 = ws[EX_WBT + u * 4 + 3];
#pragma unroll
        for (int k = 0; k < 2; ++k) {
            float da = fmaf(a0, s3[k][0], fmaf(a1, s3[k][1], fmaf(a2, s3[k][2], a3 * s3[k][3])));
            float db = fmaf(b0, s3[k][0], fmaf(b1, s3[k][1], fmaf(b2, s3[k][2], b3 * s3[k][3])));
            ta[k] = fmaf(s1[k][u], da, ta[k]);
            tb[k] = fmaf(s2[k][u], db, tb[k]);
        }
    }
    const float wc = ws[EX_WC3];
    float tc[2], wav[2], wbv[2];
#pragma unroll
    for (int k = 0; k < 2; ++k) {
        tc[k]  = fmaf(ws[EX_WC + 0], s3[k][0], fmaf(ws[EX_WC + 1], s3[k][1],
                 fmaf(ws[EX_WC + 2], s3[k][2], ws[EX_WC + 3] * s3[k][3])));
        wav[k] = fmaf(ws[EX_WA3 + 0], s1[k][0], fmaf(ws[EX_WA3 + 1], s1[k][1],
                 fmaf(ws[EX_WA3 + 2], s1[k][2], ws[EX_WA3 + 3] * s1[k][3])));
        wbv[k] = fmaf(ws[EX_WB3 + 0], s2[k][0], fmaf(ws[EX_WB3 + 1], s2[k][1],
                 fmaf(ws[EX_WB3 + 2], s2[k][2], ws[EX_WB3 + 3] * s2[k][3])));
    }

    float V2x[2], V2y[2], V2z[2];
#pragma unroll
    for (int k = 0; k < 2; ++k) {
        float c23x = v2[k][1] * v3[k][2] - v2[k][2] * v3[k][1];
        float c23y = v2[k][2] * v3[k][0] - v2[k][0] * v3[k][2];
        float c23z = v2[k][0] * v3[k][1] - v2[k][1] * v3[k][0];
        float c13x = v1[k][1] * v3[k][2] - v1[k][2] * v3[k][1];
        float c13y = v1[k][2] * v3[k][0] - v1[k][0] * v3[k][2];
        float c13z = v1[k][0] * v3[k][1] - v1[k][1] * v3[k][0];
        float ccrx = c12[k][1] * v3[k][2] - c12[k][2] * v3[k][1];
        float ccry = c12[k][2] * v3[k][0] - c12[k][0] * v3[k][2];
        float ccrz = c12[k][0] * v3[k][1] - c12[k][1] * v3[k][0];
        V2x[k] = sg[k] * v3[k][0] + ta[k] * v2[k][0] + tb[k] * v1[k][0]
               + tc[k] * c12[k][0] + wav[k] * c23x + wbv[k] * c13x + wc * ccrx;
        V2y[k] = sg[k] * v3[k][1] + ta[k] * v2[k][1] + tb[k] * v1[k][1]
               + tc[k] * c12[k][1] + wav[k] * c23y + wbv[k] * c13y + wc * ccry;
        V2z[k] = sg[k] * v3[k][2] + ta[k] * v2[k][2] + tb[k] * v1[k][2]
               + tc[k] * c12[k][2] + wav[k] * c23z + wbv[k] * c13z + wc * ccrz;
    }

    // ---------------- stores: 12x dwordx2 (pair outputs contiguous) -------
    const size_t n3 = (size_t)n * 3;
    const size_t base = iA * 3;             // 8B-aligned (iA even)
    if (two) {
        *(float2*)(out + base + 0)          = make_float2(acc[0][0], acc[0][1]);
        *(float2*)(out + base + 2)          = make_float2(acc[0][2], acc[1][0]);
        *(float2*)(out + base + 4)          = make_float2(acc[1][1], acc[1][2]);
        *(float2*)(out + n3 + base + 0)     = make_float2(acc[0][3], acc[0][4]);
        *(float2*)(out + n3 + base + 2)     = make_float2(acc[0][5], acc[1][3]);
        *(float2*)(out + n3 + base + 4)     = make_float2(acc[1][4], acc[1][5]);
        *(float2*)(out + 2 * n3 + base + 0) = make_float2(acc[0][6], acc[0][7]);
        *(float2*)(out + 2 * n3 + base + 2) = make_float2(acc[0][8], acc[1][6]);
        *(float2*)(out + 2 * n3 + base + 4) = make_float2(acc[1][7], acc[1][8]);
        *(float2*)(out + 3 * n3 + base + 0) = make_float2(V2x[0], V2y[0]);
        *(float2*)(out + 3 * n3 + base + 2) = make_float2(V2z[0], V2x[1]);
        *(float2*)(out + 3 * n3 + base + 4) = make_float2(V2y[1], V2z[1]);
    } else {                                // odd-n tail: item A only
        out[base + 0] = acc[0][0];
        out[base + 1] = acc[0][1];
        out[base + 2] = acc[0][2];
        out[n3 + base + 0] = acc[0][3];
        out[n3 + base + 1] = acc[0][4];
        out[n3 + base + 2] = acc[0][5];
        out[2 * n3 + base + 0] = acc[0][6];
        out[2 * n3 + base + 1] = acc[0][7];
        out[2 * n3 + base + 2] = acc[0][8];
        out[3 * n3 + base + 0] = V2x[0];
        out[3 * n3 + base + 1] = V2y[0];
        out[3 * n3 + base + 2] = V2z[0];
    }
}

extern "C" void kernel_launch(void* const* d_in, const int* in_sizes, int n_in,
                              void* d_out, int out_size, void* d_ws, size_t ws_size,
                              hipStream_t stream) {
    const float* lig = (const float*)d_in[0];
    const float* rec = (const float*)d_in[1];
    float* ws = (float*)d_ws;

    fd9_prep<<<4, 256, 0, stream>>>(
        (const float*)d_in[2], (const float*)d_in[3], (const float*)d_in[4],
        (const float*)d_in[5], (const float*)d_in[6], (const float*)d_in[7],
        (const float*)d_in[8], (const float*)d_in[9], (const float*)d_in[10],
        (const float*)d_in[11], ws);

    int n = in_sizes[0] / 12;
    int nPairs = (n + 1) / 2;
    int blocks = (nPairs + 255) / 256;
    fd9<<<blocks, 256, 0, stream>>>(lig, rec, ws, (float*)d_out, n);
}

// Round 2
// 186.426 us; speedup vs baseline: 1.1722x; 1.1722x over previous
//
#include <hip/hip_runtime.h>
#include <math.h>

// ---------------------------------------------------------------------------
// FrameDockingScoreModel — round 10.
//
// Round-9 post-mortem: dual-item interleave spilled (FETCH +20 MB / WRITE
// +7 MB of scratch traffic, VALU inst/item 2.9x r8) because both items' full
// geometry (v1,v2,v3,c12 = 48 regs) stayed live through the matvec.
//
// Round-10: keep the dual-item structure (one s_load stream feeds both
// items, half the waves, 2x input MLP) but make it spill-proof:
//  (a) epilogue hoist: V2 = sg*v3 + P where P = ta*v2+tb*v1+tc*c12+wa*c23+
//      wb*c13+wc*ccr depends only on s1/s2/s3/geometry -> computed BEFORE
//      the matvec, collapsing per-item live state to 32 floats
//      (s1,s2,s3,dots,v3,P,acc). sched_barrier(0) pins geomA | geomB |
//      matvec phases so the scheduler can't merge them.
//  (b) v_pk_fma_f32: ws 720-block repacked column-pair-major (even offsets,
//      aligned SGPR pairs) so the 9 accumulators become 4x v2f + 1 scalar:
//      20 inst/group/item instead of 45. Per-column chain order unchanged
//      -> numerics identical to r8.
// Spill-free check: FETCH ~48 GB-eq, WRITE ~47 GB-eq. pk-emitted check:
// VALU busy-time ~10 us (vs ~19 if it fell back to scalar v_fma).
// ---------------------------------------------------------------------------

#define K_A   (0.10846522890932808f * 0.24253562503633297f)  // C2_000*C1_000
#define K_B   (0.10846522890932808f * 0.14002800840979312f)  // C2_000*C1_110
#define K_P   (0.06262242910851495f * 0.33333333333333333f)  // C2_110*C1_011
#define K_Q   (0.06262242910851495f * 0.33333333333333333f)  // C2_110*C1_101
#define K_R   (0.06262242910851495f * 0.23570226039551584f)  // C2_110*C1_111
#define K_WB  (0.14907119849998599f * 0.24253562503633297f)  // C2_011*C1_000
#define K_CB  (0.14907119849998599f * 0.14002800840979312f)  // C2_011*C1_110
#define K_WA  (0.14907119849998599f * 0.33333333333333333f)  // C2_101*C1_011
#define K_WBT (0.14907119849998599f * 0.33333333333333333f)  // C2_101*C1_101
#define K_WC  (0.14907119849998599f * 0.23570226039551584f)  // C2_101*C1_111
#define K_WA3 (0.10540925533894598f * 0.33333333333333333f)  // C2_111*C1_011
#define K_WB3 (0.10540925533894598f * 0.33333333333333333f)  // C2_111*C1_101
#define K_WC3 (0.10540925533894598f * 0.23570226039551584f)  // C2_111*C1_111

// ws layout: 20 groups x 36 floats (pair-major: colpair p base 8p, row r at
// +2r, col8 block at +32+r), then extras (unchanged offsets).
#define EX_WB   720   // 16
#define EX_CB   736   // 1 (737..739 pad)
#define EX_WA   740   // 16
#define EX_WBT  756   // 16
#define EX_WC   772   // 4
#define EX_WA3  776   // 4
#define EX_WB3  780   // 4
#define EX_WC3  784   // 1
#define N_WS    785

typedef float v2f __attribute__((ext_vector_type(2)));

__global__ void fd10_prep(const float* __restrict__ w1_000, const float* __restrict__ w1_110,
                          const float* __restrict__ w1_011, const float* __restrict__ w1_101,
                          const float* __restrict__ w1_111, const float* __restrict__ w2_000,
                          const float* __restrict__ w2_110, const float* __restrict__ w2_011,
                          const float* __restrict__ w2_101, const float* __restrict__ w2_111,
                          float* __restrict__ ws)
{
    int j = blockIdx.x * 256 + threadIdx.x;
    if (j >= N_WS) return;
    float val = 0.f;
    if (j < 720) {
        // pair-major group layout -> recover (global row R, col c)
        int g = j / 36, slot = j - g * 36;
        int r, c;
        if (slot < 32) { r = (slot & 7) >> 1; c = ((slot >> 3) << 1) + (slot & 1); }
        else           { r = slot - 32;       c = 8; }
        int R = 4 * g + r;
        if (R < 64) {                       // s1(x)s2(x)s3 rows
            int pq = R >> 2, v = R & 3;
            float a = 0.f;
            for (int u = 0; u < 20; ++u)
                a = fmaf(w1_000[pq * 20 + u], w2_000[u * 36 + v * 9 + c], a);
            val = K_A * a;
        } else if (R < 68) {                // dot12*s3 rows
            int v = R - 64; float a = 0.f;
            for (int u = 0; u < 20; ++u)
                a = fmaf(w1_110[u], w2_000[u * 36 + v * 9 + c], a);
            val = K_B * a;
        } else if (R < 72) {                // d23*s1 rows
            int u = R - 68; float a = 0.f;
            for (int m = 0; m < 5; ++m)
                a = fmaf(w1_011[u * 5 + m], w2_110[m * 9 + c], a);
            val = K_P * a;
        } else if (R < 76) {                // d13*s2 rows
            int u = R - 72; float a = 0.f;
            for (int m = 0; m < 5; ++m)
                a = fmaf(w1_101[u * 5 + m], w2_110[m * 9 + c], a);
            val = K_Q * a;
        } else if (R == 76) {               // dtp row
            float a = 0.f;
            for (int m = 0; m < 5; ++m)
                a = fmaf(w1_111[m], w2_110[m * 9 + c], a);
            val = K_R * a;
        }                                   // rows 77..79: zero
    } else {
        int k = j - 720;
        if (k < 16) {                       // WB[pq]
            float a = 0.f;
            for (int u = 0; u < 20; ++u)
                a = fmaf(w2_011[u], w1_000[k * 20 + u], a);
            val = K_WB * a;
        } else if (k == 16) {               // CB
            float a = 0.f;
            for (int u = 0; u < 20; ++u)
                a = fmaf(w2_011[u], w1_110[u], a);
            val = K_CB * a;
        } else if (k >= 20 && k < 36) {     // WA[u*4+v]
            int u = (k - 20) >> 2, v = (k - 20) & 3;
            float a = 0.f;
            for (int m = 0; m < 5; ++m)
                a = fmaf(w1_011[u * 5 + m], w2_101[m * 4 + v], a);
            val = K_WA * a;
        } else if (k >= 36 && k < 52) {     // WBT[u*4+v]
            int u = (k - 36) >> 2, v = (k - 36) & 3;
            float a = 0.f;
            for (int m = 0; m < 5; ++m)
                a = fmaf(w1_101[u * 5 + m], w2_101[m * 4 + v], a);
            val = K_WBT * a;
        } else if (k >= 52 && k < 56) {     // WC[v]
            int v = k - 52; float a = 0.f;
            for (int m = 0; m < 5; ++m)
                a = fmaf(w1_111[m], w2_101[m * 4 + v], a);
            val = K_WC * a;
        } else if (k >= 56 && k < 60) {     // WA3[u]
            int u = k - 56; float a = 0.f;
            for (int m = 0; m < 5; ++m)
                a = fmaf(w2_111[m], w1_011[u * 5 + m], a);
            val = K_WA3 * a;
        } else if (k >= 60 && k < 64) {     // WB3[v]
            int v = k - 60; float a = 0.f;
            for (int m = 0; m < 5; ++m)
                a = fmaf(w2_111[m], w1_101[v * 5 + m], a);
            val = K_WB3 * a;
        } else if (k == 64) {               // WC3
            float a = 0.f;
            for (int m = 0; m < 5; ++m)
                a = fmaf(w2_111[m], w1_111[m], a);
            val = K_WC3 * a;
        }
    }
    ws[j] = val;
}

// Per-item state kept live through the matvec: 32 floats.
struct ItemState {
    float s1[4], s2[4], s3[4];
    float dot12, d13, d23, dtp;
    float v3x, v3y, v3z;
    float px, py, pz;     // epilogue-hoisted V2 partial (all but the sg*v3 term)
};

__device__ __forceinline__ ItemState geom(const float4 l0, const float4 l1, const float4 l2,
                                          const float4 r0, const float4 r1, const float4 r2,
                                          const float* __restrict__ ws)
{
    ItemState st;
    float e1x = l0.w - r0.w, e1y = l1.x - r1.x, e1z = l1.y - r1.y;
    float e2x = l1.z - r1.z, e2y = l1.w - r1.w, e2z = l2.x - r2.x;
    float e3x = l2.y - r2.y, e3y = l2.z - r2.z, e3z = l2.w - r2.w;

    float n1 = fmaf(e1x, e1x, fmaf(e1y, e1y, e1z * e1z));
    float n2 = fmaf(e2x, e2x, fmaf(e2y, e2y, e2z * e2z));
    float n3q = fmaf(e3x, e3x, fmaf(e3y, e3y, e3z * e3z));
    float i1 = __builtin_amdgcn_rsqf(n1);
    float i2 = __builtin_amdgcn_rsqf(n2);
    float i3 = __builtin_amdgcn_rsqf(n3q);
    float d1 = n1 * i1, d2 = n2 * i2, d3 = n3q * i3;

    float v1x = e1x * i1, v1y = e1y * i1, v1z = e1z * i1;
    float v2x = e2x * i2, v2y = e2y * i2, v2z = e2z * i2;
    st.v3x = e3x * i3; st.v3y = e3y * i3; st.v3z = e3z * i3;

    const float coeff = -0.18f;
    const float o1 = 1.6666666f, o2 = 3.3333333f, o3 = 5.f;
    float x;
    x = d1;      st.s1[0] = __expf(coeff * x * x);
    x = d1 - o1; st.s1[1] = __expf(coeff * x * x);
    x = d1 - o2; st.s1[2] = __expf(coeff * x * x);
    x = d1 - o3; st.s1[3] = __expf(coeff * x * x);
    x = d2;      st.s2[0] = __expf(coeff * x * x);
    x = d2 - o1; st.s2[1] = __expf(coeff * x * x);
    x = d2 - o2; st.s2[2] = __expf(coeff * x * x);
    x = d2 - o3; st.s2[3] = __expf(coeff * x * x);
    x = d3;      st.s3[0] = __expf(coeff * x * x);
    x = d3 - o1; st.s3[1] = __expf(coeff * x * x);
    x = d3 - o2; st.s3[2] = __expf(coeff * x * x);
    x = d3 - o3; st.s3[3] = __expf(coeff * x * x);

    st.dot12 = v1x * v2x + v1y * v2y + v1z * v2z;
    st.d13   = v1x * st.v3x + v1y * st.v3y + v1z * st.v3z;
    st.d23   = v2x * st.v3x + v2y * st.v3y + v2z * st.v3z;
    float c12x = v1y * v2z - v1z * v2y;
    float c12y = v1z * v2x - v1x * v2z;
    float c12z = v1x * v2y - v1y * v2x;
    st.dtp = c12x * st.v3x + c12y * st.v3y + c12z * st.v3z;

    // ---- epilogue scalars (depend only on s1/s2/s3 + ws extras) ----
    float ta = 0.f, tb = 0.f;
#pragma unroll
    for (int u = 0; u < 4; ++u) {
        float da = fmaf(ws[EX_WA + u * 4 + 0], st.s3[0], fmaf(ws[EX_WA + u * 4 + 1], st.s3[1],
                   fmaf(ws[EX_WA + u * 4 + 2], st.s3[2], ws[EX_WA + u * 4 + 3] * st.s3[3])));
        float db = fmaf(ws[EX_WBT + u * 4 + 0], st.s3[0], fmaf(ws[EX_WBT + u * 4 + 1], st.s3[1],
                   fmaf(ws[EX_WBT + u * 4 + 2], st.s3[2], ws[EX_WBT + u * 4 + 3] * st.s3[3])));
        ta = fmaf(st.s1[u], da, ta);
        tb = fmaf(st.s2[u], db, tb);
    }
    float tc = fmaf(ws[EX_WC + 0], st.s3[0], fmaf(ws[EX_WC + 1], st.s3[1],
               fmaf(ws[EX_WC + 2], st.s3[2], ws[EX_WC + 3] * st.s3[3])));
    float wa = fmaf(ws[EX_WA3 + 0], st.s1[0], fmaf(ws[EX_WA3 + 1], st.s1[1],
               fmaf(ws[EX_WA3 + 2], st.s1[2], ws[EX_WA3 + 3] * st.s1[3])));
    float wb = fmaf(ws[EX_WB3 + 0], st.s2[0], fmaf(ws[EX_WB3 + 1], st.s2[1],
               fmaf(ws[EX_WB3 + 2], st.s2[2], ws[EX_WB3 + 3] * st.s2[3])));
    float wc = ws[EX_WC3];

    float c23x = v2y * st.v3z - v2z * st.v3y;
    float c23y = v2z * st.v3x - v2x * st.v3z;
    float c23z = v2x * st.v3y - v2y * st.v3x;
    float c13x = v1y * st.v3z - v1z * st.v3y;
    float c13y = v1z * st.v3x - v1x * st.v3z;
    float c13z = v1x * st.v3y - v1y * st.v3x;
    float ccrx = c12y * st.v3z - c12z * st.v3y;
    float ccry = c12z * st.v3x - c12x * st.v3z;
    float ccrz = c12x * st.v3y - c12y * st.v3x;

    st.px = ta * v2x + tb * v1x + tc * c12x + wa * c23x + wb * c13x + wc * ccrx;
    st.py = ta * v2y + tb * v1y + tc * c12y + wa * c23y + wb * c13y + wc * ccry;
    st.pz = ta * v2z + tb * v1z + tc * c12z + wa * c23z + wb * c13z + wc * ccrz;
    return st;
}

__global__ __launch_bounds__(256) void
fd10(const float* __restrict__ lig, const float* __restrict__ rec,
     const float* __restrict__ ws, float* __restrict__ out, int n)
{
    const int t = blockIdx.x * 256 + threadIdx.x;
    const size_t iA = (size_t)t * 2;
    if (iA >= (size_t)n) return;
    const bool two = (iA + 1) < (size_t)n;
    const size_t iB = two ? iA + 1 : iA;

    // 12 dwordx4 issued upfront (2x MLP vs single-item)
    const float4* LA = (const float4*)(lig + iA * 12);
    const float4* RA = (const float4*)(rec + iA * 12);
    const float4* LB = (const float4*)(lig + iB * 12);
    const float4* RB = (const float4*)(rec + iB * 12);
    float4 lA0 = LA[0], lA1 = LA[1], lA2 = LA[2];
    float4 rA0 = RA[0], rA1 = RA[1], rA2 = RA[2];
    float4 lB0 = LB[0], lB1 = LB[1], lB2 = LB[2];
    float4 rB0 = RB[0], rB1 = RB[1], rB2 = RB[2];

    // Phase-pinned: geom A | geom B | matvec. Keeps peak pressure at
    // (one item in flight) + (other item's 32-float state).
    ItemState A = geom(lA0, lA1, lA2, rA0, rA1, rA2, ws);
    __builtin_amdgcn_sched_barrier(0);
    ItemState B = geom(lB0, lB1, lB2, rB0, rB1, rB2, ws);
    __builtin_amdgcn_sched_barrier(0);

    // ---------------- 77-row matvec, dual items, pk-fma ----------------
    v2f a01A = {0.f, 0.f}, a23A = {0.f, 0.f}, a45A = {0.f, 0.f}, a67A = {0.f, 0.f};
    v2f a01B = {0.f, 0.f}, a23B = {0.f, 0.f}, a45B = {0.f, 0.f}, a67B = {0.f, 0.f};
    float a8A = 0.f, a8B = 0.f;

#define FMA2(x_, wptr_, accv_) accv_ = __builtin_elementwise_fma((v2f){(x_), (x_)}, *(const v2f*)(wptr_), accv_)

    // One s_load stream (36 dwords, pair-aligned) feeds both items.
    // Per-column accumulation order identical to r8.
#define GROUP4D(g, xa0, xa1, xa2, xa3, xb0, xb1, xb2, xb3) do { \
    const float* wp_ = ws + 36 * (g); \
    const float a0_ = (xa0), a1_ = (xa1), a2_ = (xa2), a3_ = (xa3); \
    const float b0_ = (xb0), b1_ = (xb1), b2_ = (xb2), b3_ = (xb3); \
    FMA2(a0_, wp_ +  0, a01A); FMA2(a0_, wp_ +  8, a23A); FMA2(a0_, wp_ + 16, a45A); FMA2(a0_, wp_ + 24, a67A); a8A = fmaf(a0_, wp_[32], a8A); \
    FMA2(b0_, wp_ +  0, a01B); FMA2(b0_, wp_ +  8, a23B); FMA2(b0_, wp_ + 16, a45B); FMA2(b0_, wp_ + 24, a67B); a8B = fmaf(b0_, wp_[32], a8B); \
    FMA2(a1_, wp_ +  2, a01A); FMA2(a1_, wp_ + 10, a23A); FMA2(a1_, wp_ + 18, a45A); FMA2(a1_, wp_ + 26, a67A); a8A = fmaf(a1_, wp_[33], a8A); \
    FMA2(b1_, wp_ +  2, a01B); FMA2(b1_, wp_ + 10, a23B); FMA2(b1_, wp_ + 18, a45B); FMA2(b1_, wp_ + 26, a67B); a8B = fmaf(b1_, wp_[33], a8B); \
    FMA2(a2_, wp_ +  4, a01A); FMA2(a2_, wp_ + 12, a23A); FMA2(a2_, wp_ + 20, a45A); FMA2(a2_, wp_ + 28, a67A); a8A = fmaf(a2_, wp_[34], a8A); \
    FMA2(b2_, wp_ +  4, a01B); FMA2(b2_, wp_ + 12, a23B); FMA2(b2_, wp_ + 20, a45B); FMA2(b2_, wp_ + 28, a67B); a8B = fmaf(b2_, wp_[34], a8B); \
    FMA2(a3_, wp_ +  6, a01A); FMA2(a3_, wp_ + 14, a23A); FMA2(a3_, wp_ + 22, a45A); FMA2(a3_, wp_ + 30, a67A); a8A = fmaf(a3_, wp_[35], a8A); \
    FMA2(b3_, wp_ +  6, a01B); FMA2(b3_, wp_ + 14, a23B); FMA2(b3_, wp_ + 22, a45B); FMA2(b3_, wp_ + 30, a67B); a8B = fmaf(b3_, wp_[35], a8B); \
} while (0)

    const float cb = ws[EX_CB];
    float sgA = A.dot12 * cb, sgB = B.dot12 * cb;

#pragma unroll
    for (int p = 0; p < 4; ++p) {
#pragma unroll
        for (int q = 0; q < 4; ++q) {
            const int pq = p * 4 + q;
            const float oA = A.s1[p] * A.s2[q];
            const float oB = B.s1[p] * B.s2[q];
            const float wbq = ws[EX_WB + pq];
            sgA = fmaf(oA, wbq, sgA);
            sgB = fmaf(oB, wbq, sgB);
            GROUP4D(pq, oA * A.s3[0], oA * A.s3[1], oA * A.s3[2], oA * A.s3[3],
                        oB * B.s3[0], oB * B.s3[1], oB * B.s3[2], oB * B.s3[3]);
        }
    }
    GROUP4D(16, A.dot12 * A.s3[0], A.dot12 * A.s3[1], A.dot12 * A.s3[2], A.dot12 * A.s3[3],
                B.dot12 * B.s3[0], B.dot12 * B.s3[1], B.dot12 * B.s3[2], B.dot12 * B.s3[3]);
    GROUP4D(17, A.d23 * A.s1[0], A.d23 * A.s1[1], A.d23 * A.s1[2], A.d23 * A.s1[3],
                B.d23 * B.s1[0], B.d23 * B.s1[1], B.d23 * B.s1[2], B.d23 * B.s1[3]);
    GROUP4D(18, A.d13 * A.s2[0], A.d13 * A.s2[1], A.d13 * A.s2[2], A.d13 * A.s2[3],
                B.d13 * B.s2[0], B.d13 * B.s2[1], B.d13 * B.s2[2], B.d13 * B.s2[3]);
    {   // group 19: row 76 only (rows 77..79 zero)
        const float* wp = ws + 36 * 19;
        FMA2(A.dtp, wp +  0, a01A); FMA2(A.dtp, wp +  8, a23A);
        FMA2(A.dtp, wp + 16, a45A); FMA2(A.dtp, wp + 24, a67A); a8A = fmaf(A.dtp, wp[32], a8A);
        FMA2(B.dtp, wp +  0, a01B); FMA2(B.dtp, wp +  8, a23B);
        FMA2(B.dtp, wp + 16, a45B); FMA2(B.dtp, wp + 24, a67B); a8B = fmaf(B.dtp, wp[32], a8B);
    }
#undef GROUP4D
#undef FMA2

    // ---------------- finish V2 = sg*v3 + P ----------------
    float V2xA = fmaf(sgA, A.v3x, A.px);
    float V2yA = fmaf(sgA, A.v3y, A.py);
    float V2zA = fmaf(sgA, A.v3z, A.pz);
    float V2xB = fmaf(sgB, B.v3x, B.px);
    float V2yB = fmaf(sgB, B.v3y, B.py);
    float V2zB = fmaf(sgB, B.v3z, B.pz);

    // ---------------- stores: 12x dwordx2 (pair outputs contiguous) -------
    const size_t n3 = (size_t)n * 3;
    const size_t base = iA * 3;             // 8B-aligned (iA even)
    if (two) {
        *(float2*)(out + base + 0)          = make_float2(a01A[0], a01A[1]);
        *(float2*)(out + base + 2)          = make_float2(a23A[0], a01B[0]);
        *(float2*)(out + base + 4)          = make_float2(a01B[1], a23B[0]);
        *(float2*)(out + n3 + base + 0)     = make_float2(a23A[1], a45A[0]);
        *(float2*)(out + n3 + base + 2)     = make_float2(a45A[1], a23B[1]);
        *(float2*)(out + n3 + base + 4)     = make_float2(a45B[0], a45B[1]);
        *(float2*)(out + 2 * n3 + base + 0) = make_float2(a67A[0], a67A[1]);
        *(float2*)(out + 2 * n3 + base + 2) = make_float2(a8A, a67B[0]);
        *(float2*)(out + 2 * n3 + base + 4) = make_float2(a67B[1], a8B);
        *(float2*)(out + 3 * n3 + base + 0) = make_float2(V2xA, V2yA);
        *(float2*)(out + 3 * n3 + base + 2) = make_float2(V2zA, V2xB);
        *(float2*)(out + 3 * n3 + base + 4) = make_float2(V2yB, V2zB);
    } else {                                // odd-n tail: item A only
        out[base + 0] = a01A[0];
        out[base + 1] = a01A[1];
        out[base + 2] = a23A[0];
        out[n3 + base + 0] = a23A[1];
        out[n3 + base + 1] = a45A[0];
        out[n3 + base + 2] = a45A[1];
        out[2 * n3 + base + 0] = a67A[0];
        out[2 * n3 + base + 1] = a67A[1];
        out[2 * n3 + base + 2] = a8A;
        out[3 * n3 + base + 0] = V2xA;
        out[3 * n3 + base + 1] = V2yA;
        out[3 * n3 + base + 2] = V2zA;
    }
}

extern "C" void kernel_launch(void* const* d_in, const int* in_sizes, int n_in,
                              void* d_out, int out_size, void* d_ws, size_t ws_size,
                              hipStream_t stream) {
    const float* lig = (const float*)d_in[0];
    const float* rec = (const float*)d_in[1];
    float* ws = (float*)d_ws;

    fd10_prep<<<4, 256, 0, stream>>>(
        (const float*)d_in[2], (const float*)d_in[3], (const float*)d_in[4],
        (const float*)d_in[5], (const float*)d_in[6], (const float*)d_in[7],
        (const float*)d_in[8], (const float*)d_in[9], (const float*)d_in[10],
        (const float*)d_in[11], ws);

    int n = in_sizes[0] / 12;
    int nPairs = (n + 1) / 2;
    int blocks = (nPairs + 255) / 256;
    fd10<<<blocks, 256, 0, stream>>>(lig, rec, ws, (float*)d_out, n);
}

// Round 3
// 164.996 us; speedup vs baseline: 1.3245x; 1.1299x over previous
//
#include <hip/hip_runtime.h>
#include <math.h>

// ---------------------------------------------------------------------------
// FrameDockingScoreModel — round 11.
//
// r9/r10 post-mortem: both dual-item variants doubled per-item VALU cycles
// (r9: scratch spill, FETCH/WRITE inflated; r10: pk-fma is double-pumped on
// CDNA (4 cyc = 2 scalar FMAs, zero savings), splat-pair v_movs, and v2f
// loads defeating the uniform-load->s_load scalarization). r8's 52.6 us had
// per-item VALU 3,060 cyc; both rewrites paid ~6,300.
//
// Round-11: r8 codegen byte-for-byte (scalar fmaf matvec, row-major ws,
// s_load weights, scalar stores), ONE change: each thread handles items
// t and t+T (T=n/2), all 12 input dwordx4 issued up front, then
// [compute+store A] | sched_barrier(0) | [compute+store B]. B's HBM latency
// hides under A's ~3k-cycle compute; waves halve; only B's 24 raw input
// floats are live across compute-A (vs r9's 50+ derived floats -> no spill).
// Results bitwise-identical to r8.
// Checks: WRITE_SIZE == 46875 KB exactly (no spill); VALU busy-time ~20 us
// total (per-item VALU restored); predicted fd11 dur 33-40 us.
// ---------------------------------------------------------------------------

#define K_A   (0.10846522890932808f * 0.24253562503633297f)  // C2_000*C1_000
#define K_B   (0.10846522890932808f * 0.14002800840979312f)  // C2_000*C1_110
#define K_P   (0.06262242910851495f * 0.33333333333333333f)  // C2_110*C1_011
#define K_Q   (0.06262242910851495f * 0.33333333333333333f)  // C2_110*C1_101
#define K_R   (0.06262242910851495f * 0.23570226039551584f)  // C2_110*C1_111
#define K_WB  (0.14907119849998599f * 0.24253562503633297f)  // C2_011*C1_000
#define K_CB  (0.14907119849998599f * 0.14002800840979312f)  // C2_011*C1_110
#define K_WA  (0.14907119849998599f * 0.33333333333333333f)  // C2_101*C1_011
#define K_WBT (0.14907119849998599f * 0.33333333333333333f)  // C2_101*C1_101
#define K_WC  (0.14907119849998599f * 0.23570226039551584f)  // C2_101*C1_111
#define K_WA3 (0.10540925533894598f * 0.33333333333333333f)  // C2_111*C1_011
#define K_WB3 (0.10540925533894598f * 0.33333333333333333f)  // C2_111*C1_101
#define K_WC3 (0.10540925533894598f * 0.23570226039551584f)  // C2_111*C1_111

// ws layout: 80 rows x 9 floats (rows 77..79 zero) = 720, then extras
#define EX_WB   720   // 16
#define EX_CB   736   // 1 (737..739 pad)
#define EX_WA   740   // 16
#define EX_WBT  756   // 16
#define EX_WC   772   // 4
#define EX_WA3  776   // 4
#define EX_WB3  780   // 4
#define EX_WC3  784   // 1
#define N_WS    785

__global__ void fd11_prep(const float* __restrict__ w1_000, const float* __restrict__ w1_110,
                          const float* __restrict__ w1_011, const float* __restrict__ w1_101,
                          const float* __restrict__ w1_111, const float* __restrict__ w2_000,
                          const float* __restrict__ w2_110, const float* __restrict__ w2_011,
                          const float* __restrict__ w2_101, const float* __restrict__ w2_111,
                          float* __restrict__ ws)
{
    int j = blockIdx.x * 256 + threadIdx.x;
    if (j >= N_WS) return;
    float val = 0.f;
    if (j < 720) {
        int r = j / 9, c = j - r * 9;
        if (r < 64) {                       // s1(x)s2(x)s3 rows
            int pq = r >> 2, v = r & 3;
            float a = 0.f;
            for (int u = 0; u < 20; ++u)
                a = fmaf(w1_000[pq * 20 + u], w2_000[u * 36 + v * 9 + c], a);
            val = K_A * a;
        } else if (r < 68) {                // dot12*s3 rows
            int v = r - 64; float a = 0.f;
            for (int u = 0; u < 20; ++u)
                a = fmaf(w1_110[u], w2_000[u * 36 + v * 9 + c], a);
            val = K_B * a;
        } else if (r < 72) {                // d23*s1 rows
            int u = r - 68; float a = 0.f;
            for (int m = 0; m < 5; ++m)
                a = fmaf(w1_011[u * 5 + m], w2_110[m * 9 + c], a);
            val = K_P * a;
        } else if (r < 76) {                // d13*s2 rows
            int u = r - 72; float a = 0.f;
            for (int m = 0; m < 5; ++m)
                a = fmaf(w1_101[u * 5 + m], w2_110[m * 9 + c], a);
            val = K_Q * a;
        } else if (r == 76) {               // dtp row
            float a = 0.f;
            for (int m = 0; m < 5; ++m)
                a = fmaf(w1_111[m], w2_110[m * 9 + c], a);
            val = K_R * a;
        }                                   // rows 77..79: zero
    } else {
        int k = j - 720;
        if (k < 16) {                       // WB[pq]
            float a = 0.f;
            for (int u = 0; u < 20; ++u)
                a = fmaf(w2_011[u], w1_000[k * 20 + u], a);
            val = K_WB * a;
        } else if (k == 16) {               // CB
            float a = 0.f;
            for (int u = 0; u < 20; ++u)
                a = fmaf(w2_011[u], w1_110[u], a);
            val = K_CB * a;
        } else if (k >= 20 && k < 36) {     // WA[u*4+v]
            int u = (k - 20) >> 2, v = (k - 20) & 3;
            float a = 0.f;
            for (int m = 0; m < 5; ++m)
                a = fmaf(w1_011[u * 5 + m], w2_101[m * 4 + v], a);
            val = K_WA * a;
        } else if (k >= 36 && k < 52) {     // WBT[u*4+v]
            int u = (k - 36) >> 2, v = (k - 36) & 3;
            float a = 0.f;
            for (int m = 0; m < 5; ++m)
                a = fmaf(w1_101[u * 5 + m], w2_101[m * 4 + v], a);
            val = K_WBT * a;
        } else if (k >= 52 && k < 56) {     // WC[v]
            int v = k - 52; float a = 0.f;
            for (int m = 0; m < 5; ++m)
                a = fmaf(w1_111[m], w2_101[m * 4 + v], a);
            val = K_WC * a;
        } else if (k >= 56 && k < 60) {     // WA3[u]
            int u = k - 56; float a = 0.f;
            for (int m = 0; m < 5; ++m)
                a = fmaf(w2_111[m], w1_011[u * 5 + m], a);
            val = K_WA3 * a;
        } else if (k >= 60 && k < 64) {     // WB3[v]
            int v = k - 60; float a = 0.f;
            for (int m = 0; m < 5; ++m)
                a = fmaf(w2_111[m], w1_101[v * 5 + m], a);
            val = K_WB3 * a;
        } else if (k == 64) {               // WC3
            float a = 0.f;
            for (int m = 0; m < 5; ++m)
                a = fmaf(w2_111[m], w1_111[m], a);
            val = K_WC3 * a;
        }
    }
    ws[j] = val;
}

// The exact r8 per-item body: geometry -> 77-row matvec -> epilogue -> stores.
// Weights via wave-uniform ws loads (backend scalarizes to s_load; SGPR
// operands are free in the FMAs). FMA order identical to r8.
__device__ __forceinline__ void
fd11_item(const float4 l0, const float4 l1, const float4 l2,
          const float4 r0, const float4 r1, const float4 r2,
          const float* __restrict__ ws, float* __restrict__ out,
          const size_t idx, const size_t n3, const bool doStore)
{
    float e1x = l0.w - r0.w, e1y = l1.x - r1.x, e1z = l1.y - r1.y;
    float e2x = l1.z - r1.z, e2y = l1.w - r1.w, e2z = l2.x - r2.x;
    float e3x = l2.y - r2.y, e3y = l2.z - r2.z, e3z = l2.w - r2.w;

    float n1 = fmaf(e1x, e1x, fmaf(e1y, e1y, e1z * e1z));
    float n2 = fmaf(e2x, e2x, fmaf(e2y, e2y, e2z * e2z));
    float n3sq = fmaf(e3x, e3x, fmaf(e3y, e3y, e3z * e3z));
    float i1 = __builtin_amdgcn_rsqf(n1);
    float i2 = __builtin_amdgcn_rsqf(n2);
    float i3 = __builtin_amdgcn_rsqf(n3sq);
    float d1 = n1 * i1, d2 = n2 * i2, d3 = n3sq * i3;

    float v1x = e1x * i1, v1y = e1y * i1, v1z = e1z * i1;
    float v2x = e2x * i2, v2y = e2y * i2, v2z = e2z * i2;
    float v3x = e3x * i3, v3y = e3y * i3, v3z = e3z * i3;

    const float coeff = -0.18f;
    const float o1 = 1.6666666f, o2 = 3.3333333f, o3 = 5.f;
    float s1[4], s2[4], s3[4];
    float x;
    x = d1;      s1[0] = __expf(coeff * x * x);
    x = d1 - o1; s1[1] = __expf(coeff * x * x);
    x = d1 - o2; s1[2] = __expf(coeff * x * x);
    x = d1 - o3; s1[3] = __expf(coeff * x * x);
    x = d2;      s2[0] = __expf(coeff * x * x);
    x = d2 - o1; s2[1] = __expf(coeff * x * x);
    x = d2 - o2; s2[2] = __expf(coeff * x * x);
    x = d2 - o3; s2[3] = __expf(coeff * x * x);
    x = d3;      s3[0] = __expf(coeff * x * x);
    x = d3 - o1; s3[1] = __expf(coeff * x * x);
    x = d3 - o2; s3[2] = __expf(coeff * x * x);
    x = d3 - o3; s3[3] = __expf(coeff * x * x);

    float dot12 = v1x * v2x + v1y * v2y + v1z * v2z;
    float d13   = v1x * v3x + v1y * v3y + v1z * v3z;
    float d23   = v2x * v3x + v2y * v3y + v2z * v3z;
    float c12x = v1y * v2z - v1z * v2y;
    float c12y = v1z * v2x - v1x * v2z;
    float c12z = v1x * v2y - v1y * v2x;
    float dtp  = c12x * v3x + c12y * v3y + c12z * v3z;

    // ---------------- 77-row matvec, 9 scalar accumulators ----------------
    float acc0 = 0.f, acc1 = 0.f, acc2 = 0.f, acc3 = 0.f, acc4 = 0.f;
    float acc5 = 0.f, acc6 = 0.f, acc7 = 0.f, acc8 = 0.f;

#define GROUP4(g, x0v, x1v, x2v, x3v) do { \
    const float* wp_ = ws + 36 * (g); \
    const float x0_ = (x0v), x1_ = (x1v), x2_ = (x2v), x3_ = (x3v); \
    acc0 = fmaf(x0_, wp_[0], acc0);  acc1 = fmaf(x0_, wp_[1], acc1); \
    acc2 = fmaf(x0_, wp_[2], acc2);  acc3 = fmaf(x0_, wp_[3], acc3); \
    acc4 = fmaf(x0_, wp_[4], acc4);  acc5 = fmaf(x0_, wp_[5], acc5); \
    acc6 = fmaf(x0_, wp_[6], acc6);  acc7 = fmaf(x0_, wp_[7], acc7); \
    acc8 = fmaf(x0_, wp_[8], acc8); \
    acc0 = fmaf(x1_, wp_[9], acc0);  acc1 = fmaf(x1_, wp_[10], acc1); \
    acc2 = fmaf(x1_, wp_[11], acc2); acc3 = fmaf(x1_, wp_[12], acc3); \
    acc4 = fmaf(x1_, wp_[13], acc4); acc5 = fmaf(x1_, wp_[14], acc5); \
    acc6 = fmaf(x1_, wp_[15], acc6); acc7 = fmaf(x1_, wp_[16], acc7); \
    acc8 = fmaf(x1_, wp_[17], acc8); \
    acc0 = fmaf(x2_, wp_[18], acc0); acc1 = fmaf(x2_, wp_[19], acc1); \
    acc2 = fmaf(x2_, wp_[20], acc2); acc3 = fmaf(x2_, wp_[21], acc3); \
    acc4 = fmaf(x2_, wp_[22], acc4); acc5 = fmaf(x2_, wp_[23], acc5); \
    acc6 = fmaf(x2_, wp_[24], acc6); acc7 = fmaf(x2_, wp_[25], acc7); \
    acc8 = fmaf(x2_, wp_[26], acc8); \
    acc0 = fmaf(x3_, wp_[27], acc0); acc1 = fmaf(x3_, wp_[28], acc1); \
    acc2 = fmaf(x3_, wp_[29], acc2); acc3 = fmaf(x3_, wp_[30], acc3); \
    acc4 = fmaf(x3_, wp_[31], acc4); acc5 = fmaf(x3_, wp_[32], acc5); \
    acc6 = fmaf(x3_, wp_[33], acc6); acc7 = fmaf(x3_, wp_[34], acc7); \
    acc8 = fmaf(x3_, wp_[35], acc8); \
} while (0)

    float sg = dot12 * ws[EX_CB];

#pragma unroll
    for (int p = 0; p < 4; ++p) {
#pragma unroll
        for (int q = 0; q < 4; ++q) {
            const int pq = p * 4 + q;
            float o = s1[p] * s2[q];
            sg = fmaf(o, ws[EX_WB + pq], sg);
            GROUP4(pq, o * s3[0], o * s3[1], o * s3[2], o * s3[3]);
        }
    }
    GROUP4(16, dot12 * s3[0], dot12 * s3[1], dot12 * s3[2], dot12 * s3[3]);
    GROUP4(17, d23 * s1[0], d23 * s1[1], d23 * s1[2], d23 * s1[3]);
    GROUP4(18, d13 * s2[0], d13 * s2[1], d13 * s2[2], d13 * s2[3]);
    {   // row 76 only (77..79 are zero)
        const float* wp = ws + 36 * 19;
        acc0 = fmaf(dtp, wp[0], acc0); acc1 = fmaf(dtp, wp[1], acc1);
        acc2 = fmaf(dtp, wp[2], acc2); acc3 = fmaf(dtp, wp[3], acc3);
        acc4 = fmaf(dtp, wp[4], acc4); acc5 = fmaf(dtp, wp[5], acc5);
        acc6 = fmaf(dtp, wp[6], acc6); acc7 = fmaf(dtp, wp[7], acc7);
        acc8 = fmaf(dtp, wp[8], acc8);
    }
#undef GROUP4

    // ---------------- epilogue scalars ----------------
    float ta = 0.f, tb = 0.f;
#pragma unroll
    for (int u = 0; u < 4; ++u) {
        float da = fmaf(ws[EX_WA + u * 4 + 0], s3[0], fmaf(ws[EX_WA + u * 4 + 1], s3[1],
                   fmaf(ws[EX_WA + u * 4 + 2], s3[2], ws[EX_WA + u * 4 + 3] * s3[3])));
        float db = fmaf(ws[EX_WBT + u * 4 + 0], s3[0], fmaf(ws[EX_WBT + u * 4 + 1], s3[1],
                   fmaf(ws[EX_WBT + u * 4 + 2], s3[2], ws[EX_WBT + u * 4 + 3] * s3[3])));
        ta = fmaf(s1[u], da, ta);
        tb = fmaf(s2[u], db, tb);
    }
    float tc = fmaf(ws[EX_WC + 0], s3[0], fmaf(ws[EX_WC + 1], s3[1],
               fmaf(ws[EX_WC + 2], s3[2], ws[EX_WC + 3] * s3[3])));
    float wa = fmaf(ws[EX_WA3 + 0], s1[0], fmaf(ws[EX_WA3 + 1], s1[1],
               fmaf(ws[EX_WA3 + 2], s1[2], ws[EX_WA3 + 3] * s1[3])));
    float wb = fmaf(ws[EX_WB3 + 0], s2[0], fmaf(ws[EX_WB3 + 1], s2[1],
               fmaf(ws[EX_WB3 + 2], s2[2], ws[EX_WB3 + 3] * s2[3])));
    float wc = ws[EX_WC3];

    float c23x = v2y * v3z - v2z * v3y;
    float c23y = v2z * v3x - v2x * v3z;
    float c23z = v2x * v3y - v2y * v3x;
    float c13x = v1y * v3z - v1z * v3y;
    float c13y = v1z * v3x - v1x * v3z;
    float c13z = v1x * v3y - v1y * v3x;
    float ccrx = c12y * v3z - c12z * v3y;
    float ccry = c12z * v3x - c12x * v3z;
    float ccrz = c12x * v3y - c12y * v3x;

    float V2x = sg * v3x + ta * v2x + tb * v1x + tc * c12x + wa * c23x + wb * c13x + wc * ccrx;
    float V2y = sg * v3y + ta * v2y + tb * v1y + tc * c12y + wa * c23y + wb * c13y + wc * ccry;
    float V2z = sg * v3z + ta * v2z + tb * v1z + tc * c12z + wa * c23z + wb * c13z + wc * ccrz;

    // ---------------- stores (r8 pattern: lanes stride-3, wave-contiguous) -
    if (doStore) {
        const size_t base = idx * 3;
        out[base + 0] = acc0;
        out[base + 1] = acc1;
        out[base + 2] = acc2;
        out[n3 + base + 0] = acc3;
        out[n3 + base + 1] = acc4;
        out[n3 + base + 2] = acc5;
        out[2 * n3 + base + 0] = acc6;
        out[2 * n3 + base + 1] = acc7;
        out[2 * n3 + base + 2] = acc8;
        out[3 * n3 + base + 0] = V2x;
        out[3 * n3 + base + 1] = V2y;
        out[3 * n3 + base + 2] = V2z;
    }
}

__global__ __launch_bounds__(256) void
fd11(const float* __restrict__ lig, const float* __restrict__ rec,
     const float* __restrict__ ws, float* __restrict__ out, int n)
{
    const int T = (n + 1) >> 1;                    // items per half
    const int t = blockIdx.x * 256 + threadIdx.x;
    if (t >= T) return;

    const size_t iA = (size_t)t;
    const size_t iBr = (size_t)t + (size_t)T;      // second-half item
    const bool hasB = iBr < (size_t)n;             // false only for odd-n tail
    const size_t iB = hasB ? iBr : iA;             // clamp: loads valid, store guarded

    // ---- issue ALL input loads up front: 12 dwordx4 in flight ----
    const float4* LA = (const float4*)(lig + iA * 12);
    const float4* RA = (const float4*)(rec + iA * 12);
    const float4* LB = (const float4*)(lig + iB * 12);
    const float4* RB = (const float4*)(rec + iB * 12);
    float4 lA0 = LA[0], lA1 = LA[1], lA2 = LA[2];
    float4 rA0 = RA[0], rA1 = RA[1], rA2 = RA[2];
    float4 lB0 = LB[0], lB1 = LB[1], lB2 = LB[2];
    float4 rB0 = RB[0], rB1 = RB[1], rB2 = RB[2];

    const size_t n3 = (size_t)n * 3;

    // compute+store A while B's loads are in flight; barrier pins the phases
    // so the scheduler cannot interleave the two bodies (r9's pressure trap).
    fd11_item(lA0, lA1, lA2, rA0, rA1, rA2, ws, out, iA, n3, true);
    __builtin_amdgcn_sched_barrier(0);
    fd11_item(lB0, lB1, lB2, rB0, rB1, rB2, ws, out, iBr, n3, hasB);
}

extern "C" void kernel_launch(void* const* d_in, const int* in_sizes, int n_in,
                              void* d_out, int out_size, void* d_ws, size_t ws_size,
                              hipStream_t stream) {
    const float* lig = (const float*)d_in[0];
    const float* rec = (const float*)d_in[1];
    float* ws = (float*)d_ws;

    fd11_prep<<<4, 256, 0, stream>>>(
        (const float*)d_in[2], (const float*)d_in[3], (const float*)d_in[4],
        (const float*)d_in[5], (const float*)d_in[6], (const float*)d_in[7],
        (const float*)d_in[8], (const float*)d_in[9], (const float*)d_in[10],
        (const float*)d_in[11], ws);

    int n = in_sizes[0] / 12;
    int T = (n + 1) / 2;
    int blocks = (T + 255) / 256;
    fd11<<<blocks, 256, 0, stream>>>(lig, rec, ws, (float*)d_out, n);
}